// Round 11
// baseline (127.020 us; speedup 1.0000x reference)
//
#include <hip/hip_runtime.h>

// FirUpsample R10 = R9 structure, unconfounded:
//   R9's launch_bounds(512,4) capped VGPR at 64 -> acc[4] (64 f32) spilled to
//   scratch (VGPR_Count=64, WRITE 65->167MB, MfmaUtil halved). R10 uses
//   (512,2) -> 128 VGPR, no spill, still 2 blocks/CU (16 waves/CU, 2x R5-R8).
//   Also reverts to octile-per-XCD swizzle (R9's spatial grouping put 5.3MB
//   in a 4MB L2 -> thrash, FETCH +10MB; octile slice is 295KB, x via L3).
// Math (verified R5-R9, absmax 0.015625): h = dilated conv3x3 as 4 parity-
// plane GEMMs (10.3 G MAC) staged in LDS bf16; separable 4-tap FIR epilogue.

typedef short bf16x4 __attribute__((ext_vector_type(4)));
typedef short bf16x8 __attribute__((ext_vector_type(8)));
typedef short short4v __attribute__((ext_vector_type(4)));
typedef float f32x16 __attribute__((ext_vector_type(16)));
typedef float f32x4v __attribute__((ext_vector_type(4)));

static __device__ __forceinline__ short f2bf(float f) {
  union { float f; unsigned u; } v; v.f = f;
  unsigned r = (v.u + 0x7FFFu + ((v.u >> 16) & 1u)) >> 16;
  return (short)r;
}
static __device__ __forceinline__ float bf2f(short s) {
  union { unsigned u; float f; } v; v.u = ((unsigned)(unsigned short)s) << 16;
  return v.f;
}

#define XS_OFF 9216   // As [0,9216) | xs [9216,14976) | hl aliases [0,12800)

__global__ __launch_bounds__(512, 2)
void fir_up_v10(const float* __restrict__ x, const float* __restrict__ w,
                float* __restrict__ out) {
  __shared__ __align__(16) char smem[14976];
  char* Ab = smem;
  char* xb = smem + XS_OFF;

  const int bid = blockIdx.x;
  // octile-per-XCD: wg = xcd*128 + k -> octile = wg>>7 == xcd (bid&7).
  const int wg = (bid & 7) * 128 + (bid >> 3);
  const int octile = wg >> 7;          // == bid&7: w-slice 295KB L2-resident
  const int sp = wg & 127;
  const int n = sp >> 5;
  const int atile = (sp >> 2) & 7;
  const int btile = sp & 3;
  const int A0 = atile * 8, B0 = btile * 16;

  const int tid = threadIdx.x;
  const int wid = tid >> 6;
  const int lane = tid & 63;
  const int l31 = lane & 31, q = lane >> 5;

  // ---- plane geometry (verbatim R8/R9, verified) ----
  const int COLSt[4]  = {17, 18, 17, 18};
  const int CELLSt[4] = {153, 162, 170, 180};
  const int NKt[4]    = {4, 2, 2, 1};
  const int KQt[4][4] = {{0,2,6,8},{1,7,7,7},{3,5,5,5},{4,4,4,4}};
  const int DYt[4][4] = {{0,0,1,1},{0,1,1,1},{0,0,0,0},{0,0,0,0}};
  const int DXt[4][4] = {{0,1,0,1},{0,0,0,0},{0,1,1,1},{0,0,0,0}};
  const int SEG0P[8]   = {0,0,0,1,1,2,2,3};
  const int SEG0FGB[8] = {0,2,4,0,3,0,3,0};
  const int SEG0NFG[8] = {2,2,1,3,3,3,3,4};

  const int p0w = SEG0P[wid];
  const int nk0 = NKt[p0w];
  const int nfg0 = SEG0NFG[wid];
  int aoff0[4];
#pragma unroll
  for (int s = 0; s < 4; ++s)
    aoff0[s] = KQt[p0w][s] * 1024 + l31 * 32 + ((q * 16) ^ ((l31 & 4) << 2));
  int boff0[4][4], valid0[4], hbase0[4];
#pragma unroll
  for (int fg = 0; fg < 4; ++fg) {
    const int cellraw = (SEG0FGB[wid] + fg) * 32 + l31;
    const int valid = cellraw < CELLSt[p0w];
    const int cell = valid ? cellraw : 0;
    const int cols = COLSt[p0w];
    const int r = cell / cols;
    const int c = cell - r * cols;
    valid0[fg] = valid;
    hbase0[fg] = p0w * 1600 + r * 20 + c;
#pragma unroll
    for (int s = 0; s < 4; ++s) {
      const int bc = (r + DYt[p0w][s]) * 18 + (c + DXt[p0w][s]);
      boff0[fg][s] = bc * 32 + ((q * 16) ^ ((bc & 4) << 2));
    }
  }
  const int aoff1 = 4 * 1024 + l31 * 32 + ((q * 16) ^ ((l31 & 4) << 2));
  int boff1[2], valid1[2], hbase1[2];
#pragma unroll
  for (int j = 0; j < 2; ++j) {
    const int cellraw = (4 + j) * 32 + l31;
    const int valid = cellraw < 180;
    const int cell = valid ? cellraw : 0;
    const int r = cell / 18;
    const int c = cell - r * 18;
    valid1[j] = valid;
    hbase1[j] = 3 * 1600 + r * 20 + c;
    boff1[j] = cell * 32 + ((q * 16) ^ ((cell & 4) << 2));
  }

  f32x16 acc[4];
#pragma unroll
  for (int fg = 0; fg < 4; ++fg)
#pragma unroll
    for (int e = 0; e < 16; ++e) acc[fg][e] = 0.f;

  // staging constants
  const int ocA = tid >> 2, icgA = tid & 3;     // A-units: threads 0..127
  const float* wA = w + (size_t)(octile * 32 + ocA) * 2304 + icgA * 36;
  const int u = tid - 128;                      // x-units: threads 128..487
  const int ucell = u >> 1, uhalf = u & 1;
  const int uhh = ucell / 18, uww = ucell - uhh * 18;
  const int ugh = A0 - 1 + uhh, ugw = B0 - 1 + uww;
  const bool uok = (ugh >= 0) & (ugh < 64) & (ugw >= 0) & (ugw < 64);
  const float* uxp = x + (((size_t)(n * 256 + uhalf * 8)) * 64 + ugh) * 64 + ugw;
  const int uwb = ucell * 32 + ((uhalf * 16) ^ ((ucell & 4) << 2));

  // ---------------- K-loop: 16 chunks of 16 ic ----------------
  for (int cc = 0; cc < 16; ++cc) {
    if (tid < 128) {
      float f36[36];
      const float* wp = wA + cc * 144;
#pragma unroll
      for (int f4 = 0; f4 < 9; ++f4)
        *(f32x4v*)&f36[f4 * 4] = *(const f32x4v*)(wp + f4 * 4);
#pragma unroll
      for (int kq = 0; kq < 9; ++kq) {
        bf16x4 pk;
#pragma unroll
        for (int v = 0; v < 4; ++v) pk[v] = f2bf(f36[v * 9 + kq]);
        const int byte = kq * 1024 + ocA * 32 + ((icgA * 8) ^ ((ocA & 4) << 2));
        *(bf16x4*)(Ab + byte) = pk;
      }
    } else if (tid < 488) {
      const float* xp = uxp + (size_t)cc * 16 * 4096;
      bf16x8 vv;
#pragma unroll
      for (int e = 0; e < 8; ++e) {
        const float f = uok ? xp[(size_t)e * 4096] : 0.f;
        vv[e] = f2bf(f);
      }
      *(bf16x8*)(xb + uwb) = vv;
    }
    __syncthreads();

#pragma unroll
    for (int s = 0; s < 4; ++s) {
      if (s < nk0) {
        const bf16x8 A = *(const bf16x8*)(Ab + aoff0[s]);
#pragma unroll
        for (int fg = 0; fg < 4; ++fg) {
          if (fg < nfg0) {
            const bf16x8 B = *(const bf16x8*)(xb + boff0[fg][s]);
            acc[fg] = __builtin_amdgcn_mfma_f32_32x32x16_bf16(A, B, acc[fg], 0, 0, 0);
          }
        }
      }
    }
    if (wid == 2) {
      const bf16x8 A = *(const bf16x8*)(Ab + aoff1);
#pragma unroll
      for (int j = 0; j < 2; ++j) {
        const bf16x8 B = *(const bf16x8*)(xb + boff1[j]);
        acc[1 + j] = __builtin_amdgcn_mfma_f32_32x32x16_bf16(A, B, acc[1 + j], 0, 0, 0);
      }
    }
    __syncthreads();  // readers done before next restage
  }

  // ---------------- epilogue: 4 sub-phases of 8 ocs; hl aliases As/xs ----------------
  short* hl = (short*)smem;
  const float kf4[4] = {0.25f, 0.75f, 0.75f, 0.25f};
#pragma unroll
  for (int g8 = 0; g8 < 4; ++g8) {
#pragma unroll
    for (int fg = 0; fg < 4; ++fg) {
      if (fg < nfg0 && valid0[fg]) {
#pragma unroll
        for (int jj = 0; jj < 4; ++jj)
          hl[hbase0[fg] + (jj + 4 * q) * 200] = f2bf(acc[fg][4 * g8 + jj]);
      }
    }
    if (wid == 2) {
#pragma unroll
      for (int j = 0; j < 2; ++j) {
        if (valid1[j]) {
#pragma unroll
          for (int jj = 0; jj < 4; ++jj)
            hl[hbase1[j] + (jj + 4 * q) * 200] = f2bf(acc[1 + j][4 * g8 + jj]);
        }
      }
    }
    __syncthreads();

    const int g = tid & 3;
    const int Yl = (tid >> 2) & 15;
    const int o8 = tid >> 6;
    float o[8];
#pragma unroll
    for (int xx = 0; xx < 8; ++xx) o[xx] = 0.f;
#pragma unroll
    for (int du = 0; du < 4; ++du) {
      const int ttp = Yl - 1 + du;
      const int py = ttp & 1;
      const int r = py ? ((Yl + du) >> 1) : (ttp >> 1);
      const int baseE = (py * 2) * 1600 + o8 * 200 + r * 20 + 4 * g;
      const int baseO = baseE + 1600;
      const short4v e0 = *(const short4v*)(hl + baseE);
      const short4v e1 = *(const short4v*)(hl + baseE + 4);
      const short4v o0 = *(const short4v*)(hl + baseO);
      const short4v o1 = *(const short4v*)(hl + baseO + 4);
      float E[8], O[8];
#pragma unroll
      for (int i = 0; i < 4; ++i) {
        E[i] = bf2f(e0[i]); E[i + 4] = bf2f(e1[i]);
        O[i] = bf2f(o0[i]); O[i + 4] = bf2f(o1[i]);
      }
      float rx[8];
      rx[0] = 0.25f*O[0] + 0.75f*E[0] + 0.75f*O[1] + 0.25f*E[1];
      rx[1] = 0.25f*E[0] + 0.75f*O[1] + 0.75f*E[1] + 0.25f*O[2];
      rx[2] = 0.25f*O[1] + 0.75f*E[1] + 0.75f*O[2] + 0.25f*E[2];
      rx[3] = 0.25f*E[1] + 0.75f*O[2] + 0.75f*E[2] + 0.25f*O[3];
      rx[4] = 0.25f*O[2] + 0.75f*E[2] + 0.75f*O[3] + 0.25f*E[3];
      rx[5] = 0.25f*E[2] + 0.75f*O[3] + 0.75f*E[3] + 0.25f*O[4];
      rx[6] = 0.25f*O[3] + 0.75f*E[3] + 0.75f*O[4] + 0.25f*E[4];
      rx[7] = 0.25f*E[3] + 0.75f*O[4] + 0.75f*E[4] + 0.25f*O[5];
      const float ky = kf4[du];
#pragma unroll
      for (int xx = 0; xx < 8; ++xx) o[xx] += ky * rx[xx];
    }
    const int oc = octile * 32 + g8 * 8 + o8;
    const int Y = atile * 16 + Yl;
    const int X0 = btile * 32 + g * 8;
    float* op = out + (((size_t)(n * 256 + oc)) * 128 + Y) * 128 + X0;
    f32x4v v0, v1;
    v0[0] = o[0]; v0[1] = o[1]; v0[2] = o[2]; v0[3] = o[3];
    v1[0] = o[4]; v1[1] = o[5]; v1[2] = o[6]; v1[3] = o[7];
    *(f32x4v*)op = v0;
    *(f32x4v*)(op + 4) = v1;
    __syncthreads();  // hl free for next sub-phase
  }
}

extern "C" void kernel_launch(void* const* d_in, const int* in_sizes, int n_in,
                              void* d_out, int out_size, void* d_ws, size_t ws_size,
                              hipStream_t stream) {
  (void)in_sizes; (void)n_in; (void)out_size; (void)d_ws; (void)ws_size;
  const float* x = (const float*)d_in[0];
  const float* w = (const float*)d_in[1];
  float* out = (float*)d_out;
  // grid = 8 octiles x 4 n x 8 atiles x 4 btiles = 1024 blocks, 512 threads
  hipLaunchKernelGGL(fir_up_v10, dim3(1024), dim3(512), 0, stream, x, w, out);
}